// Round 8
// baseline (2023.544 us; speedup 1.0000x reference)
//
#include <hip/hip_runtime.h>
#include <hip/hip_bf16.h>

#define LOG2E 1.4426950408889634f

typedef float f32x4 __attribute__((ext_vector_type(4)));
typedef __bf16 bf16x8 __attribute__((ext_vector_type(8)));
typedef unsigned short u16x8 __attribute__((ext_vector_type(8)));

typedef __attribute__((address_space(1))) void gvoid_t;
typedef __attribute__((address_space(3))) void lvoid_t;

#define MFMA(a, b, c) __builtin_amdgcn_mfma_f32_16x16x32_bf16( \
    __builtin_bit_cast(bf16x8, (a)), __builtin_bit_cast(bf16x8, (b)), (c), 0, 0, 0)

__device__ __forceinline__ unsigned short f2bf(float f) {
  unsigned int u = __builtin_bit_cast(unsigned int, f);
  u += 0x7fffu + ((u >> 16) & 1u);
  return (unsigned short)(u >> 16);
}

__device__ __forceinline__ void cp16(const void* g, void* l) {
  __builtin_amdgcn_global_load_lds((gvoid_t*)g, (lvoid_t*)l, 16, 0, 0);
}

// ---------------- pack / convert kernels ----------------

__global__ __launch_bounds__(256) void k_cvt_x(const float* __restrict__ x,
                                               unsigned short* __restrict__ xb) {
  int i = blockIdx.x * 256 + threadIdx.x;
  float4 v = ((const float4*)x)[i];
  ushort4 o;
  o.x = f2bf(v.x); o.y = f2bf(v.y); o.z = f2bf(v.z); o.w = f2bf(v.w);
  ((ushort4*)xb)[i] = o;
}

// wq/wk/wv [h][d][e] fp32 -> wt [which][h][e][d] bf16 (B^T layout per head)
__global__ __launch_bounds__(256) void k_pack_w(const float* __restrict__ wq,
                                                const float* __restrict__ wk,
                                                const float* __restrict__ wv,
                                                unsigned short* __restrict__ wt) {
  __shared__ float t[64][65];
  int tid = threadIdx.x;
  int z = blockIdx.z;
  int which = z >> 3;
  int h = z & 7;
  const float* src = (which == 0 ? wq : which == 1 ? wk : wv) + (size_t)h * 512 * 512;
  int d0 = blockIdx.x * 64, e0 = blockIdx.y * 64;
  for (int i = 0; i < 4; ++i) {
    int idx = i * 256 + tid;
    int r = idx >> 4, c = (idx & 15) * 4;
    float4 v = *(const float4*)&src[(size_t)(d0 + r) * 512 + e0 + c];
    t[r][c] = v.x; t[r][c + 1] = v.y; t[r][c + 2] = v.z; t[r][c + 3] = v.w;
  }
  __syncthreads();
  unsigned short* dst = wt + ((size_t)z * 512 + e0) * 512 + d0;
  for (int i = 0; i < 4; ++i) {
    int idx = i * 256 + tid;
    int r = idx >> 4, c = (idx & 15) * 4;
    ushort4 o;
    o.x = f2bf(t[c][r]); o.y = f2bf(t[c + 1][r]);
    o.z = f2bf(t[c + 2][r]); o.w = f2bf(t[c + 3][r]);
    *(ushort4*)&dst[(size_t)r * 512 + c] = o;
  }
}

// wo [4096][512] fp32 -> wot [512][4096] bf16
__global__ __launch_bounds__(256) void k_pack_wo(const float* __restrict__ wo,
                                                 unsigned short* __restrict__ wot) {
  __shared__ float t[64][65];
  int tid = threadIdx.x;
  int r0 = blockIdx.y * 64;
  int c0 = blockIdx.x * 64;
  for (int i = 0; i < 4; ++i) {
    int idx = i * 256 + tid;
    int r = idx >> 4, c = (idx & 15) * 4;
    float4 v = *(const float4*)&wo[(size_t)(r0 + r) * 512 + c0 + c];
    t[r][c] = v.x; t[r][c + 1] = v.y; t[r][c + 2] = v.z; t[r][c + 3] = v.w;
  }
  __syncthreads();
  unsigned short* dst = wot + (size_t)c0 * 4096 + r0;
  for (int i = 0; i < 4; ++i) {
    int idx = i * 256 + tid;
    int r = idx >> 4, c = (idx & 15) * 4;
    ushort4 o;
    o.x = f2bf(t[c][r]); o.y = f2bf(t[c + 1][r]);
    o.z = f2bf(t[c + 2][r]); o.w = f2bf(t[c + 3][r]);
    *(ushort4*)&dst[(size_t)r * 4096 + c] = o;
  }
}

// cos/sin table: cs[c][j] for position c, pair j = e/2
__global__ void k_cs(float2* __restrict__ cs) {
  int c = blockIdx.x, i = threadIdx.x;
  float theta = powf(10000.0f, -2.0f * (float)i / 512.0f);
  float ang = (float)c * theta;
  float2 v;
  v.x = cosf(ang);
  v.y = sinf(ang);
  cs[c * 256 + i] = v;
}

// ---------------- shared 128x128 tile GEMM core (bf16, A[M,K] x Bt[N,K]) ----------------

__device__ __forceinline__ void gemm_core(const unsigned short* __restrict__ A, int lda,
                                          const unsigned short* __restrict__ Bt, int ldb,
                                          int K, f32x4 (&acc)[4][4],
                                          unsigned short* sA, unsigned short* sB) {
  const int tid = threadIdx.x;
  const int lane = tid & 63;
  const int w = tid >> 6;
  const int wm = (w >> 1) * 64;
  const int wn = (w & 1) * 64;

  const int ra = tid >> 2, ca = tid & 3;
  const int rb = (tid + 256) >> 2, cb = (tid + 256) & 3;
  const int sa = (ca ^ ((ra >> 1) & 3)) * 8;
  const int sb = (cb ^ ((rb >> 1) & 3)) * 8;

  const int kk = (lane >> 4) * 8;
  const int rowA = wm + (lane & 15);
  const int rowB = wn + (lane & 15);

  for (int k0 = 0; k0 < K; k0 += 32) {
    cp16(A + (size_t)ra * lda + k0 + sa, sA + (size_t)tid * 8);
    cp16(A + (size_t)rb * lda + k0 + sb, sA + (size_t)(tid + 256) * 8);
    cp16(Bt + (size_t)ra * ldb + k0 + sa, sB + (size_t)tid * 8);
    cp16(Bt + (size_t)rb * ldb + k0 + sb, sB + (size_t)(tid + 256) * 8);
    __syncthreads();
    u16x8 a[4], b[4];
#pragma unroll
    for (int i = 0; i < 4; ++i) {
      int rA = rowA + i * 16;
      a[i] = *(const u16x8*)((const char*)sA + rA * 64 + ((kk * 2) ^ (((rA >> 1) & 3) << 4)));
      int rB = rowB + i * 16;
      b[i] = *(const u16x8*)((const char*)sB + rB * 64 + ((kk * 2) ^ (((rB >> 1) & 3) << 4)));
    }
#pragma unroll
    for (int mi = 0; mi < 4; ++mi)
#pragma unroll
      for (int ni = 0; ni < 4; ++ni)
        acc[mi][ni] = MFMA(a[mi], b[ni], acc[mi][ni]);
    __syncthreads();
  }
}

// ---------------- QK projection GEMM + bias + RoPE (per head-group) ----------------

__global__ __launch_bounds__(256) void k_gemm_qk(const unsigned short* __restrict__ xb,
                                                 const unsigned short* __restrict__ wt,
                                                 const float* __restrict__ bq,
                                                 const float* __restrict__ bk,
                                                 const float2* __restrict__ cs,
                                                 unsigned short* __restrict__ qb,
                                                 unsigned short* __restrict__ kb,
                                                 int hp_log2, int h_off) {
  __shared__ unsigned short sA[128 * 32];
  __shared__ unsigned short sB[128 * 32];
  int m0 = blockIdx.x * 128;
  int n0g = blockIdx.y * 128;
  int which = n0g >> (9 + hp_log2);
  int hl = (n0g >> 9) & ((1 << hp_log2) - 1);
  int e0 = n0g & 511;
  int h = h_off + hl;
  const unsigned short* Bt = wt + ((size_t)(which * 8 + h) * 512 + e0) * 512;
  f32x4 acc[4][4] = {};
  gemm_core(xb + (size_t)m0 * 512, 512, Bt, 512, 512, acc, sA, sB);

  int lane = threadIdx.x & 63;
  int w = threadIdx.x >> 6;
  int wm = (w >> 1) * 64, wn = (w & 1) * 64;
  const float* bias = which ? bk : bq;
  unsigned short* outb = which ? kb : qb;
#pragma unroll
  for (int mi = 0; mi < 4; ++mi) {
#pragma unroll
    for (int ni = 0; ni < 4; ++ni) {
      f32x4 v = acc[mi][ni];
      int e = e0 + wn + ni * 16 + (lane & 15);
      float bcol = bias[h * 512 + e];
#pragma unroll
      for (int r = 0; r < 4; ++r) {
        int m = m0 + wm + mi * 16 + (lane >> 4) * 4 + r;
        int b = m >> 11, c = m & 2047;
        float val = v[r] + bcol;
        float partner = __shfl_xor(val, 1, 64);
        float2 f = cs[(size_t)c * 256 + (e >> 1)];
        float rot = (e & 1) ? (f.y * partner + f.x * val)
                            : (f.x * val - f.y * partner);
        outb[(((size_t)(hl * 4 + b) * 2048 + c) * 512) + e] = f2bf(rot);
      }
    }
  }
}

// ---------------- V^T projection GEMM (per head-group) ----------------

__global__ __launch_bounds__(256) void k_gemm_vt(const unsigned short* __restrict__ xb,
                                                 const unsigned short* __restrict__ wt,
                                                 const float* __restrict__ bv,
                                                 unsigned short* __restrict__ vt,
                                                 int row_off) {
  __shared__ unsigned short sA[128 * 32];
  __shared__ unsigned short sB[128 * 32];
  int m0 = blockIdx.x * 128;  // local (hl,e)
  int n0 = blockIdx.y * 128;  // (b,c)
  const unsigned short* Arows = wt + (size_t)16 * 512 * 512 + (size_t)(row_off + m0) * 512;
  f32x4 acc[4][4] = {};
  gemm_core(Arows, 512, xb + (size_t)n0 * 512, 512, 512, acc, sA, sB);

  int lane = threadIdx.x & 63;
  int w = threadIdx.x >> 6;
  int wm = (w >> 1) * 64, wn = (w & 1) * 64;
#pragma unroll
  for (int mi = 0; mi < 4; ++mi) {
#pragma unroll
    for (int ni = 0; ni < 4; ++ni) {
      f32x4 v = acc[mi][ni];
      int n = n0 + wn + ni * 16 + (lane & 15);
      int b = n >> 11, c = n & 2047;
#pragma unroll
      for (int r = 0; r < 4; ++r) {
        int m = m0 + wm + mi * 16 + (lane >> 4) * 4 + r;  // local hl*512+e
        int hl = m >> 9, e = m & 511;
        float val = v[r] + bv[row_off + m];
        vt[(((size_t)(hl * 4 + b) * 512 + e) * 2048) + c] = f2bf(val);
      }
    }
  }
}

// ---------------- flash attention ----------------
// Block: 512 thr (8 waves). Two same-hb passes per block: (qtA, hbl) and
// (15-qtA, hbl), qtA in 0..7 -> uniform 34 tiles/block, single (h,b) per block.
// Pipelined staging: K(t+1) issued after softmax barrier (hidden under PV),
// V(t+1) issued after PV barrier (hidden under next QK+softmax).

__device__ __forceinline__ void attn_pass(const unsigned short* __restrict__ Qg,
                                          const unsigned short* __restrict__ Kg,
                                          const unsigned short* __restrict__ Vg,
                                          unsigned short* __restrict__ ao,
                                          int q0, int b, int h,
                                          unsigned short* Ks, unsigned short* Vs,
                                          unsigned short* Ps, float* fscale, float* lbuf) {
  const int tid = threadIdx.x;
  const int lane = tid & 63;
  const int w = tid >> 6;

  u16x8 qf[16];
  {
    int row = q0 + w * 16 + (lane & 15);
    int kkq = (lane >> 4) * 8;
#pragma unroll
    for (int ks = 0; ks < 16; ++ks)
      qf[ks] = *(const u16x8*)&Qg[(size_t)row * 512 + ks * 32 + kkq];
  }

  f32x4 accO[4][8] = {};
  float mrun[4], lrun[4];
#pragma unroll
  for (int r = 0; r < 4; ++r) { mrun[r] = -1e30f; lrun[r] = 0.0f; }

  const int T = q0 / 64 + 2;
  const float sc = 0.044194173824159216f;  // 1/sqrt(512)
  const int wq2 = w >> 2, wd = w & 3;

  // prologue: stage tile 0 (K and V), source-side swizzle
#pragma unroll
  for (int i = 0; i < 8; ++i) {
    int cid = i * 512 + tid;
    int kv = cid >> 6, c = cid & 63;
    int csrc = c ^ (kv & 7);
    cp16(Kg + (size_t)kv * 512 + csrc * 8, (char*)Ks + cid * 16);
  }
#pragma unroll
  for (int i = 0; i < 8; ++i) {
    int cid = i * 512 + tid;
    int d = cid >> 3, c = cid & 7;
    int csrc = c ^ (d & 7);
    cp16(Vg + (size_t)d * 2048 + csrc * 8, (char*)Vs + cid * 16);
  }
  __syncthreads();

  for (int t = 0; t < T; ++t) {
    const int kv0 = t * 64;

    // ---- QK^T (reads Ks) ----
    f32x4 accS[4] = {};
#pragma unroll
    for (int ks = 0; ks < 16; ++ks) {
#pragma unroll
      for (int n = 0; n < 4; ++n) {
        int kv = n * 16 + (lane & 15);
        int cbyte = ks * 64 + ((lane >> 4) << 4);
        u16x8 kfr = *(const u16x8*)((const char*)Ks + kv * 1024 + (cbyte ^ ((kv & 7) << 4)));
        accS[n] = MFMA(qf[ks], kfr, accS[n]);
      }
    }

    // ---- mask + online softmax (writes Ps, fscale) ----
    const int rowb = w * 16 + ((lane >> 4) << 2);
#pragma unroll
    for (int r = 0; r < 4; ++r) {
      int qg = q0 + rowb + r;
      float s0[4];
      float rm = -1e30f;
#pragma unroll
      for (int n = 0; n < 4; ++n) {
        int kvg = kv0 + n * 16 + (lane & 15);
        float s = accS[n][r] * sc;
        s = (kvg <= qg) ? s : -1e30f;
        s0[n] = s;
        rm = fmaxf(rm, s);
      }
      rm = fmaxf(rm, __shfl_xor(rm, 1, 64));
      rm = fmaxf(rm, __shfl_xor(rm, 2, 64));
      rm = fmaxf(rm, __shfl_xor(rm, 4, 64));
      rm = fmaxf(rm, __shfl_xor(rm, 8, 64));
      float mnew = fmaxf(mrun[r], rm);
      float f = exp2f((mrun[r] - mnew) * LOG2E);
      float rsum = 0.0f;
#pragma unroll
      for (int n = 0; n < 4; ++n) {
        float p = exp2f((s0[n] - mnew) * LOG2E);
        rsum += p;
        int col = n * 16 + (lane & 15);
        int q = rowb + r;
        *(unsigned short*)((char*)Ps + q * 128 + ((col * 2) ^ ((q & 7) << 4))) = f2bf(p);
      }
      rsum += __shfl_xor(rsum, 1, 64);
      rsum += __shfl_xor(rsum, 2, 64);
      rsum += __shfl_xor(rsum, 4, 64);
      rsum += __shfl_xor(rsum, 8, 64);
      lrun[r] = lrun[r] * f + rsum;
      mrun[r] = mnew;
      if ((lane & 15) == 0) fscale[rowb + r] = f;
    }
    __syncthreads();  // B1: Ps/fscale visible; all QK reads of Ks done; drains V(t) cp16

    // issue K(t+1) staging into now-free Ks — hidden under PV
    if (t + 1 < T) {
#pragma unroll
      for (int i = 0; i < 8; ++i) {
        int cid = i * 512 + tid;
        int kv = cid >> 6, c = cid & 63;
        int csrc = c ^ (kv & 7);
        cp16(Kg + ((size_t)(kv0 + 64 + kv)) * 512 + csrc * 8, (char*)Ks + cid * 16);
      }
    }

    // ---- PV (reads Vs, Ps, fscale) ----
#pragma unroll
    for (int mi = 0; mi < 4; ++mi) {
      int rb = wq2 * 64 + mi * 16 + ((lane >> 4) << 2);
#pragma unroll
      for (int r = 0; r < 4; ++r) {
        float f = fscale[rb + r];
#pragma unroll
        for (int ni = 0; ni < 8; ++ni) accO[mi][ni][r] *= f;
      }
    }
#pragma unroll
    for (int ks = 0; ks < 2; ++ks) {
      u16x8 vb[8];
#pragma unroll
      for (int ni = 0; ni < 8; ++ni) {
        int d = wd * 128 + ni * 16 + (lane & 15);
        int cbyte = ks * 64 + ((lane >> 4) << 4);
        vb[ni] = *(const u16x8*)((const char*)Vs + d * 128 + (cbyte ^ ((d & 7) << 4)));
      }
#pragma unroll
      for (int mi = 0; mi < 4; ++mi) {
        int q = wq2 * 64 + mi * 16 + (lane & 15);
        int cbyte = ks * 64 + ((lane >> 4) << 4);
        u16x8 pa = *(const u16x8*)((const char*)Ps + q * 128 + (cbyte ^ ((q & 7) << 4)));
#pragma unroll
        for (int ni = 0; ni < 8; ++ni)
          accO[mi][ni] = MFMA(pa, vb[ni], accO[mi][ni]);
      }
    }
    __syncthreads();  // B2: PV done -> Vs free; drains K(t+1) cp16

    // issue V(t+1) staging into now-free Vs — hidden under next QK+softmax
    if (t + 1 < T) {
#pragma unroll
      for (int i = 0; i < 8; ++i) {
        int cid = i * 512 + tid;
        int d = cid >> 3, c = cid & 7;
        int csrc = c ^ (d & 7);
        cp16(Vg + (size_t)d * 2048 + (kv0 + 64) + csrc * 8, (char*)Vs + cid * 16);
      }
    }
  }

  if ((lane & 15) == 0) {
    int rowb = w * 16 + ((lane >> 4) << 2);
#pragma unroll
    for (int r = 0; r < 4; ++r) lbuf[rowb + r] = lrun[r];
  }
  __syncthreads();

#pragma unroll
  for (int mi = 0; mi < 4; ++mi) {
    int rb = wq2 * 64 + mi * 16 + ((lane >> 4) << 2);
#pragma unroll
    for (int r = 0; r < 4; ++r) {
      float linv = 1.0f / lbuf[rb + r];
      int qg = q0 + rb + r;
      size_t base = ((size_t)b * 2048 + qg) * 4096 + h * 512 + wd * 128;
#pragma unroll
      for (int ni = 0; ni < 8; ++ni) {
        int dg = ni * 16 + (lane & 15);
        ao[base + dg] = f2bf(accO[mi][ni][r] * linv);
      }
    }
  }
}

__global__ __launch_bounds__(512) void k_attn(const unsigned short* __restrict__ qbuf,
                                              const unsigned short* __restrict__ kbuf,
                                              const unsigned short* __restrict__ vtbuf,
                                              unsigned short* __restrict__ ao,
                                              int nhb, int h_off) {
  __shared__ unsigned short Ks[64 * 512];
  __shared__ unsigned short Vs[512 * 64];
  __shared__ unsigned short Ps[128 * 64];
  __shared__ float fscale[128];
  __shared__ float lbuf[128];

  // XCD-pinned decode: all blocks of one hbl share an XCD (flat id mod 8).
  int f = blockIdx.x;
  int qtA, hbl;
  if (nhb >= 8) {
    int xcd = f & 7;
    int t2 = f >> 3;
    qtA = t2 & 7;
    hbl = xcd + 8 * (t2 >> 3);
  } else {
    qtA = f & 7;
    hbl = f >> 3;
  }
  int qtB = 15 - qtA;
  int h = h_off + (hbl >> 2), b = hbl & 3;

  const unsigned short* Qg = qbuf + (size_t)hbl * 2048 * 512;
  const unsigned short* Kg = kbuf + (size_t)hbl * 2048 * 512;
  const unsigned short* Vg = vtbuf + (size_t)hbl * 512 * 2048;

  attn_pass(Qg, Kg, Vg, ao, qtA * 128, b, h, Ks, Vs, Ps, fscale, lbuf);
  __syncthreads();
  attn_pass(Qg, Kg, Vg, ao, qtB * 128, b, h, Ks, Vs, Ps, fscale, lbuf);
}

// ---------------- output projection: out = ao[8192][4096] @ wo + bo (fp32 out) ----------------

__global__ __launch_bounds__(256) void k_gemm_out(const unsigned short* __restrict__ ao,
                                                  const unsigned short* __restrict__ wot,
                                                  const float* __restrict__ bo,
                                                  float* __restrict__ out) {
  __shared__ unsigned short sA[128 * 32];
  __shared__ unsigned short sB[128 * 32];
  int m0 = blockIdx.x * 128;
  int n0 = blockIdx.y * 128;
  f32x4 acc[4][4] = {};
  gemm_core(ao + (size_t)m0 * 4096, 4096, wot + (size_t)n0 * 4096, 4096, 4096, acc, sA, sB);

  int lane = threadIdx.x & 63;
  int w = threadIdx.x >> 6;
  int wm = (w >> 1) * 64, wn = (w & 1) * 64;
#pragma unroll
  for (int mi = 0; mi < 4; ++mi) {
#pragma unroll
    for (int ni = 0; ni < 4; ++ni) {
      f32x4 v = acc[mi][ni];
      int n = n0 + wn + ni * 16 + (lane & 15);
      float bn = bo[n];
#pragma unroll
      for (int r = 0; r < 4; ++r) {
        int m = m0 + wm + mi * 16 + (lane >> 4) * 4 + r;
        out[(size_t)m * 512 + n] = v[r] + bn;
      }
    }
  }
}

// ---------------- launch ----------------

extern "C" void kernel_launch(void* const* d_in, const int* in_sizes, int n_in,
                              void* d_out, int out_size, void* d_ws, size_t ws_size,
                              hipStream_t stream) {
  (void)in_sizes; (void)n_in; (void)out_size;
  const float* x  = (const float*)d_in[0];
  const float* wq = (const float*)d_in[1];
  const float* bq = (const float*)d_in[2];
  const float* wk = (const float*)d_in[3];
  const float* bk = (const float*)d_in[4];
  const float* wv = (const float*)d_in[5];
  const float* bv = (const float*)d_in[6];
  const float* wo = (const float*)d_in[7];
  const float* bo = (const float*)d_in[8];
  float* out = (float*)d_out;

  // Head-group count: largest G (fewest groups) whose footprint fits ws_size.
  const size_t SLAB = (size_t)4 * 2048 * 512 * 2;  // one head's q/k/v (4 batches), 8 MB
  const size_t FIXED = (size_t)8192 * 512 * 2      // xb
                     + (size_t)24 * 512 * 512 * 2  // wt
                     + (size_t)512 * 4096 * 2      // wot
                     + (size_t)2048 * 256 * 8      // cs
                     + (size_t)8192 * 4096 * 2;    // ao
  int G = 8;
  for (int g = 1; g <= 8; g <<= 1) {
    if (FIXED + 3 * (size_t)(8 / g) * SLAB <= ws_size) { G = g; break; }
  }
  const int hp = 8 / G;
  int hp_log2 = 0;
  while ((1 << hp_log2) < hp) ++hp_log2;

  char* p = (char*)d_ws;
  unsigned short* xb  = (unsigned short*)p; p += (size_t)8192 * 512 * 2;
  unsigned short* wt  = (unsigned short*)p; p += (size_t)24 * 512 * 512 * 2;
  unsigned short* wot = (unsigned short*)p; p += (size_t)512 * 4096 * 2;
  float2*         cs  = (float2*)p;         p += (size_t)2048 * 256 * 8;
  unsigned short* ao  = (unsigned short*)p; p += (size_t)8192 * 4096 * 2;
  unsigned short* qb  = (unsigned short*)p; p += (size_t)hp * SLAB;
  unsigned short* kb  = (unsigned short*)p; p += (size_t)hp * SLAB;
  unsigned short* vt  = (unsigned short*)p; p += (size_t)hp * SLAB;

  hipLaunchKernelGGL(k_cvt_x,   dim3(4096),     dim3(256), 0, stream, x, xb);
  hipLaunchKernelGGL(k_pack_w,  dim3(8, 8, 24), dim3(256), 0, stream, wq, wk, wv, wt);
  hipLaunchKernelGGL(k_pack_wo, dim3(8, 64),    dim3(256), 0, stream, wo, wot);
  hipLaunchKernelGGL(k_cs,      dim3(2048),     dim3(256), 0, stream, cs);

  for (int g = 0; g < G; ++g) {
    int nhb = 4 * hp;
    hipLaunchKernelGGL(k_gemm_qk, dim3(64, 8 * hp), dim3(256), 0, stream,
                       xb, wt, bq, bk, cs, qb, kb, hp_log2, g * hp);
    hipLaunchKernelGGL(k_gemm_vt, dim3(4 * hp, 64), dim3(256), 0, stream,
                       xb, wt, bv, vt, g * hp * 512);
    hipLaunchKernelGGL(k_attn,    dim3(8 * nhb),    dim3(512), 0, stream,
                       qb, kb, vt, ao, nhb, g * hp);
  }

  hipLaunchKernelGGL(k_gemm_out, dim3(64, 4), dim3(256), 0, stream, ao, wot, bo, out);
}

// Round 10
// 894.472 us; speedup vs baseline: 2.2623x; 2.2623x over previous
//
#include <hip/hip_runtime.h>
#include <hip/hip_bf16.h>

#define LOG2E 1.4426950408889634f

typedef float f32x4 __attribute__((ext_vector_type(4)));
typedef __bf16 bf16x8 __attribute__((ext_vector_type(8)));
typedef unsigned short u16x8 __attribute__((ext_vector_type(8)));

typedef __attribute__((address_space(1))) void gvoid_t;
typedef __attribute__((address_space(3))) void lvoid_t;

#define MFMA(a, b, c) __builtin_amdgcn_mfma_f32_16x16x32_bf16( \
    __builtin_bit_cast(bf16x8, (a)), __builtin_bit_cast(bf16x8, (b)), (c), 0, 0, 0)

__device__ __forceinline__ unsigned short f2bf(float f) {
  unsigned int u = __builtin_bit_cast(unsigned int, f);
  u += 0x7fffu + ((u >> 16) & 1u);
  return (unsigned short)(u >> 16);
}

__device__ __forceinline__ void cp16(const void* g, void* l) {
  __builtin_amdgcn_global_load_lds((gvoid_t*)g, (lvoid_t*)l, 16, 0, 0);
}

// ---------------- pack / convert kernels ----------------

__global__ __launch_bounds__(256) void k_cvt_x(const float* __restrict__ x,
                                               unsigned short* __restrict__ xb) {
  int i = blockIdx.x * 256 + threadIdx.x;
  float4 v = ((const float4*)x)[i];
  ushort4 o;
  o.x = f2bf(v.x); o.y = f2bf(v.y); o.z = f2bf(v.z); o.w = f2bf(v.w);
  ((ushort4*)xb)[i] = o;
}

// wq/wk/wv [h][d][e] fp32 -> wt [which][h][e][d] bf16 (B^T layout per head)
__global__ __launch_bounds__(256) void k_pack_w(const float* __restrict__ wq,
                                                const float* __restrict__ wk,
                                                const float* __restrict__ wv,
                                                unsigned short* __restrict__ wt) {
  __shared__ float t[64][65];
  int tid = threadIdx.x;
  int z = blockIdx.z;
  int which = z >> 3;
  int h = z & 7;
  const float* src = (which == 0 ? wq : which == 1 ? wk : wv) + (size_t)h * 512 * 512;
  int d0 = blockIdx.x * 64, e0 = blockIdx.y * 64;
  for (int i = 0; i < 4; ++i) {
    int idx = i * 256 + tid;
    int r = idx >> 4, c = (idx & 15) * 4;
    float4 v = *(const float4*)&src[(size_t)(d0 + r) * 512 + e0 + c];
    t[r][c] = v.x; t[r][c + 1] = v.y; t[r][c + 2] = v.z; t[r][c + 3] = v.w;
  }
  __syncthreads();
  unsigned short* dst = wt + ((size_t)z * 512 + e0) * 512 + d0;
  for (int i = 0; i < 4; ++i) {
    int idx = i * 256 + tid;
    int r = idx >> 4, c = (idx & 15) * 4;
    ushort4 o;
    o.x = f2bf(t[c][r]); o.y = f2bf(t[c + 1][r]);
    o.z = f2bf(t[c + 2][r]); o.w = f2bf(t[c + 3][r]);
    *(ushort4*)&dst[(size_t)r * 512 + c] = o;
  }
}

// wo [4096][512] fp32 -> wot [512][4096] bf16
__global__ __launch_bounds__(256) void k_pack_wo(const float* __restrict__ wo,
                                                 unsigned short* __restrict__ wot) {
  __shared__ float t[64][65];
  int tid = threadIdx.x;
  int r0 = blockIdx.y * 64;
  int c0 = blockIdx.x * 64;
  for (int i = 0; i < 4; ++i) {
    int idx = i * 256 + tid;
    int r = idx >> 4, c = (idx & 15) * 4;
    float4 v = *(const float4*)&wo[(size_t)(r0 + r) * 512 + c0 + c];
    t[r][c] = v.x; t[r][c + 1] = v.y; t[r][c + 2] = v.z; t[r][c + 3] = v.w;
  }
  __syncthreads();
  unsigned short* dst = wot + (size_t)c0 * 4096 + r0;
  for (int i = 0; i < 4; ++i) {
    int idx = i * 256 + tid;
    int r = idx >> 4, c = (idx & 15) * 4;
    ushort4 o;
    o.x = f2bf(t[c][r]); o.y = f2bf(t[c + 1][r]);
    o.z = f2bf(t[c + 2][r]); o.w = f2bf(t[c + 3][r]);
    *(ushort4*)&dst[(size_t)r * 4096 + c] = o;
  }
}

// cos/sin table: cs[c][j] for position c, pair j = e/2
__global__ void k_cs(float2* __restrict__ cs) {
  int c = blockIdx.x, i = threadIdx.x;
  float theta = powf(10000.0f, -2.0f * (float)i / 512.0f);
  float ang = (float)c * theta;
  float2 v;
  v.x = cosf(ang);
  v.y = sinf(ang);
  cs[c * 256 + i] = v;
}

// ---------------- shared 128x128 tile GEMM core (bf16, A[M,K] x Bt[N,K]) ----------------

__device__ __forceinline__ void gemm_core(const unsigned short* __restrict__ A, int lda,
                                          const unsigned short* __restrict__ Bt, int ldb,
                                          int K, f32x4 (&acc)[4][4],
                                          unsigned short* sA, unsigned short* sB) {
  const int tid = threadIdx.x;
  const int lane = tid & 63;
  const int w = tid >> 6;
  const int wm = (w >> 1) * 64;
  const int wn = (w & 1) * 64;

  const int ra = tid >> 2, ca = tid & 3;
  const int rb = (tid + 256) >> 2, cb = (tid + 256) & 3;
  const int sa = (ca ^ ((ra >> 1) & 3)) * 8;
  const int sb = (cb ^ ((rb >> 1) & 3)) * 8;

  const int kk = (lane >> 4) * 8;
  const int rowA = wm + (lane & 15);
  const int rowB = wn + (lane & 15);

  for (int k0 = 0; k0 < K; k0 += 32) {
    cp16(A + (size_t)ra * lda + k0 + sa, sA + (size_t)tid * 8);
    cp16(A + (size_t)rb * lda + k0 + sb, sA + (size_t)(tid + 256) * 8);
    cp16(Bt + (size_t)ra * ldb + k0 + sa, sB + (size_t)tid * 8);
    cp16(Bt + (size_t)rb * ldb + k0 + sb, sB + (size_t)(tid + 256) * 8);
    __syncthreads();
    u16x8 a[4], b[4];
#pragma unroll
    for (int i = 0; i < 4; ++i) {
      int rA = rowA + i * 16;
      a[i] = *(const u16x8*)((const char*)sA + rA * 64 + ((kk * 2) ^ (((rA >> 1) & 3) << 4)));
      int rB = rowB + i * 16;
      b[i] = *(const u16x8*)((const char*)sB + rB * 64 + ((kk * 2) ^ (((rB >> 1) & 3) << 4)));
    }
#pragma unroll
    for (int mi = 0; mi < 4; ++mi)
#pragma unroll
      for (int ni = 0; ni < 4; ++ni)
        acc[mi][ni] = MFMA(a[mi], b[ni], acc[mi][ni]);
    __syncthreads();
  }
}

// ---------------- QK projection GEMM + bias + RoPE (per head-group) ----------------

__global__ __launch_bounds__(256) void k_gemm_qk(const unsigned short* __restrict__ xb,
                                                 const unsigned short* __restrict__ wt,
                                                 const float* __restrict__ bq,
                                                 const float* __restrict__ bk,
                                                 const float2* __restrict__ cs,
                                                 unsigned short* __restrict__ qb,
                                                 unsigned short* __restrict__ kb,
                                                 int hp_log2, int h_off) {
  __shared__ unsigned short sA[128 * 32];
  __shared__ unsigned short sB[128 * 32];
  int m0 = blockIdx.x * 128;
  int n0g = blockIdx.y * 128;
  int which = n0g >> (9 + hp_log2);
  int hl = (n0g >> 9) & ((1 << hp_log2) - 1);
  int e0 = n0g & 511;
  int h = h_off + hl;
  const unsigned short* Bt = wt + ((size_t)(which * 8 + h) * 512 + e0) * 512;
  f32x4 acc[4][4] = {};
  gemm_core(xb + (size_t)m0 * 512, 512, Bt, 512, 512, acc, sA, sB);

  int lane = threadIdx.x & 63;
  int w = threadIdx.x >> 6;
  int wm = (w >> 1) * 64, wn = (w & 1) * 64;
  const float* bias = which ? bk : bq;
  unsigned short* outb = which ? kb : qb;
#pragma unroll
  for (int mi = 0; mi < 4; ++mi) {
#pragma unroll
    for (int ni = 0; ni < 4; ++ni) {
      f32x4 v = acc[mi][ni];
      int e = e0 + wn + ni * 16 + (lane & 15);
      float bcol = bias[h * 512 + e];
#pragma unroll
      for (int r = 0; r < 4; ++r) {
        int m = m0 + wm + mi * 16 + (lane >> 4) * 4 + r;
        int b = m >> 11, c = m & 2047;
        float val = v[r] + bcol;
        float partner = __shfl_xor(val, 1, 64);
        float2 f = cs[(size_t)c * 256 + (e >> 1)];
        float rot = (e & 1) ? (f.y * partner + f.x * val)
                            : (f.x * val - f.y * partner);
        outb[(((size_t)(hl * 4 + b) * 2048 + c) * 512) + e] = f2bf(rot);
      }
    }
  }
}

// ---------------- V^T projection GEMM (per head-group) ----------------

__global__ __launch_bounds__(256) void k_gemm_vt(const unsigned short* __restrict__ xb,
                                                 const unsigned short* __restrict__ wt,
                                                 const float* __restrict__ bv,
                                                 unsigned short* __restrict__ vt,
                                                 int row_off) {
  __shared__ unsigned short sA[128 * 32];
  __shared__ unsigned short sB[128 * 32];
  int m0 = blockIdx.x * 128;  // local (hl,e)
  int n0 = blockIdx.y * 128;  // (b,c)
  const unsigned short* Arows = wt + (size_t)16 * 512 * 512 + (size_t)(row_off + m0) * 512;
  f32x4 acc[4][4] = {};
  gemm_core(Arows, 512, xb + (size_t)n0 * 512, 512, 512, acc, sA, sB);

  int lane = threadIdx.x & 63;
  int w = threadIdx.x >> 6;
  int wm = (w >> 1) * 64, wn = (w & 1) * 64;
#pragma unroll
  for (int mi = 0; mi < 4; ++mi) {
#pragma unroll
    for (int ni = 0; ni < 4; ++ni) {
      f32x4 v = acc[mi][ni];
      int n = n0 + wn + ni * 16 + (lane & 15);
      int b = n >> 11, c = n & 2047;
#pragma unroll
      for (int r = 0; r < 4; ++r) {
        int m = m0 + wm + mi * 16 + (lane >> 4) * 4 + r;  // local hl*512+e
        int hl = m >> 9, e = m & 511;
        float val = v[r] + bv[row_off + m];
        vt[(((size_t)(hl * 4 + b) * 512 + e) * 2048) + c] = f2bf(val);
      }
    }
  }
}

// ---------------- flash attention ----------------
// Block: 256 thr (4 waves), QBLK=64, KVBLK=32, LDS ~68.5 KB -> 2 blocks/CU.
// Two same-hb passes per block: (qtA, hbl) and (31-qtA, hbl) -> uniform 68
// kv-tiles/block. R5-style staging: K+V staged together, ONE drain per tile;
// cross-block overlap (2 independent blocks/CU) hides the drain latency.

__device__ __forceinline__ void attn_pass(const unsigned short* __restrict__ Qg,
                                          const unsigned short* __restrict__ Kg,
                                          const unsigned short* __restrict__ Vg,
                                          unsigned short* __restrict__ ao,
                                          int q0, int b, int h,
                                          unsigned short* Ks, unsigned short* Vs,
                                          unsigned short* Ps, float* fscale, float* lbuf) {
  const int tid = threadIdx.x;   // 0..255
  const int lane = tid & 63;
  const int w = tid >> 6;        // 0..3

  // Q fragments: wave w rows q0 + w*16 + (lane&15)
  u16x8 qf[16];
  {
    int row = q0 + w * 16 + (lane & 15);
    int kkq = (lane >> 4) * 8;
#pragma unroll
    for (int ks = 0; ks < 16; ++ks)
      qf[ks] = *(const u16x8*)&Qg[(size_t)row * 512 + ks * 32 + kkq];
  }

  f32x4 accO[4][8] = {};
  float mrun[4], lrun[4];
#pragma unroll
  for (int r = 0; r < 4; ++r) { mrun[r] = -1e30f; lrun[r] = 0.0f; }

  const int T = q0 / 32 + 2;
  const float sc = 0.044194173824159216f;  // 1/sqrt(512)

  for (int t = 0; t < T; ++t) {
    const int kv0 = t * 32;
    // stage K tile [32][512]: 2048 16B granules, source-side swizzle (^ kv&7)
#pragma unroll
    for (int i = 0; i < 8; ++i) {
      int cid = i * 256 + tid;
      int kv = cid >> 6, c = cid & 63;
      int csrc = c ^ (kv & 7);
      cp16(Kg + ((size_t)(kv0 + kv)) * 512 + csrc * 8, (char*)Ks + cid * 16);
    }
    // stage V^T tile [512][32]: 2048 granules, swizzle (^ d&3)
#pragma unroll
    for (int i = 0; i < 8; ++i) {
      int cid = i * 256 + tid;
      int d = cid >> 2, c2 = cid & 3;
      int csrc = c2 ^ (d & 3);
      cp16(Vg + (size_t)d * 2048 + kv0 + csrc * 8, (char*)Vs + cid * 16);
    }
    __syncthreads();  // single drain per tile (K and V latencies overlap)

    // ---- QK^T ----
    f32x4 accS[2] = {};
#pragma unroll
    for (int ks = 0; ks < 16; ++ks) {
#pragma unroll
      for (int n = 0; n < 2; ++n) {
        int kv = n * 16 + (lane & 15);
        int cbyte = ks * 64 + ((lane >> 4) << 4);
        u16x8 kfr = *(const u16x8*)((const char*)Ks + kv * 1024 + (cbyte ^ ((kv & 7) << 4)));
        accS[n] = MFMA(qf[ks], kfr, accS[n]);
      }
    }

    // ---- mask + online softmax (16 rows per wave) ----
    const int rowb = w * 16 + ((lane >> 4) << 2);
#pragma unroll
    for (int r = 0; r < 4; ++r) {
      int qg = q0 + rowb + r;
      float s0[2];
      float rm = -1e30f;
#pragma unroll
      for (int n = 0; n < 2; ++n) {
        int kvg = kv0 + n * 16 + (lane & 15);
        float s = accS[n][r] * sc;
        s = (kvg <= qg) ? s : -1e30f;
        s0[n] = s;
        rm = fmaxf(rm, s);
      }
      rm = fmaxf(rm, __shfl_xor(rm, 1, 64));
      rm = fmaxf(rm, __shfl_xor(rm, 2, 64));
      rm = fmaxf(rm, __shfl_xor(rm, 4, 64));
      rm = fmaxf(rm, __shfl_xor(rm, 8, 64));
      float mnew = fmaxf(mrun[r], rm);
      float f = exp2f((mrun[r] - mnew) * LOG2E);
      float rsum = 0.0f;
#pragma unroll
      for (int n = 0; n < 2; ++n) {
        float p = exp2f((s0[n] - mnew) * LOG2E);
        rsum += p;
        int col = n * 16 + (lane & 15);
        int q = rowb + r;
        *(unsigned short*)((char*)Ps + q * 64 + ((col * 2) ^ ((q & 3) << 4))) = f2bf(p);
      }
      rsum += __shfl_xor(rsum, 1, 64);
      rsum += __shfl_xor(rsum, 2, 64);
      rsum += __shfl_xor(rsum, 4, 64);
      rsum += __shfl_xor(rsum, 8, 64);
      lrun[r] = lrun[r] * f + rsum;
      mrun[r] = mnew;
      if ((lane & 15) == 0) fscale[rowb + r] = f;
    }
    __syncthreads();  // Ps/fscale visible

    // ---- PV: wave w owns d-slice w*128..+128, all 64 q-rows ----
#pragma unroll
    for (int mi = 0; mi < 4; ++mi) {
      int rb = mi * 16 + ((lane >> 4) << 2);
#pragma unroll
      for (int r = 0; r < 4; ++r) {
        float f = fscale[rb + r];
#pragma unroll
        for (int ni = 0; ni < 8; ++ni) accO[mi][ni][r] *= f;
      }
    }
    {
      u16x8 vb[8];
#pragma unroll
      for (int ni = 0; ni < 8; ++ni) {
        int d = w * 128 + ni * 16 + (lane & 15);
        int cbyte = (lane >> 4) << 4;
        vb[ni] = *(const u16x8*)((const char*)Vs + d * 64 + (cbyte ^ ((d & 3) << 4)));
      }
#pragma unroll
      for (int mi = 0; mi < 4; ++mi) {
        int q = mi * 16 + (lane & 15);
        int cbyte = (lane >> 4) << 4;
        u16x8 pa = *(const u16x8*)((const char*)Ps + q * 64 + (cbyte ^ ((q & 3) << 4)));
#pragma unroll
        for (int ni = 0; ni < 8; ++ni)
          accO[mi][ni] = MFMA(pa, vb[ni], accO[mi][ni]);
      }
    }
    __syncthreads();  // Ks/Vs/Ps free for next tile
  }

  // write l, then normalize and store
  if ((lane & 15) == 0) {
    int rowb = w * 16 + ((lane >> 4) << 2);
#pragma unroll
    for (int r = 0; r < 4; ++r) lbuf[rowb + r] = lrun[r];
  }
  __syncthreads();

#pragma unroll
  for (int mi = 0; mi < 4; ++mi) {
    int rb = mi * 16 + ((lane >> 4) << 2);
#pragma unroll
    for (int r = 0; r < 4; ++r) {
      float linv = 1.0f / lbuf[rb + r];
      int qg = q0 + rb + r;
      size_t base = ((size_t)b * 2048 + qg) * 4096 + h * 512 + w * 128;
#pragma unroll
      for (int ni = 0; ni < 8; ++ni) {
        int dg = ni * 16 + (lane & 15);
        ao[base + dg] = f2bf(accO[mi][ni][r] * linv);
      }
    }
  }
}

__global__ __launch_bounds__(256) void k_attn(const unsigned short* __restrict__ qbuf,
                                              const unsigned short* __restrict__ kbuf,
                                              const unsigned short* __restrict__ vtbuf,
                                              unsigned short* __restrict__ ao,
                                              int nhb, int h_off) {
  __shared__ unsigned short Ks[32 * 512];
  __shared__ unsigned short Vs[512 * 32];
  __shared__ unsigned short Ps[64 * 32];
  __shared__ float fscale[64];
  __shared__ float lbuf[64];

  // XCD-pinned decode: all blocks of one hbl share an XCD (flat id mod 8).
  int f = blockIdx.x;
  int qtA, hbl;
  if (nhb >= 8) {
    int xcd = f & 7;
    int t2 = f >> 3;
    qtA = t2 & 15;
    hbl = xcd + 8 * (t2 >> 4);
  } else {
    qtA = f & 15;
    hbl = f >> 4;
  }
  int qtB = 31 - qtA;
  int h = h_off + (hbl >> 2), b = hbl & 3;

  const unsigned short* Qg = qbuf + (size_t)hbl * 2048 * 512;
  const unsigned short* Kg = kbuf + (size_t)hbl * 2048 * 512;
  const unsigned short* Vg = vtbuf + (size_t)hbl * 512 * 2048;

  attn_pass(Qg, Kg, Vg, ao, qtA * 64, b, h, Ks, Vs, Ps, fscale, lbuf);
  __syncthreads();
  attn_pass(Qg, Kg, Vg, ao, qtB * 64, b, h, Ks, Vs, Ps, fscale, lbuf);
}

// ---------------- output projection: out = ao[8192][4096] @ wo + bo (fp32 out) ----------------

__global__ __launch_bounds__(256) void k_gemm_out(const unsigned short* __restrict__ ao,
                                                  const unsigned short* __restrict__ wot,
                                                  const float* __restrict__ bo,
                                                  float* __restrict__ out) {
  __shared__ unsigned short sA[128 * 32];
  __shared__ unsigned short sB[128 * 32];
  int m0 = blockIdx.x * 128;
  int n0 = blockIdx.y * 128;
  f32x4 acc[4][4] = {};
  gemm_core(ao + (size_t)m0 * 4096, 4096, wot + (size_t)n0 * 4096, 4096, 4096, acc, sA, sB);

  int lane = threadIdx.x & 63;
  int w = threadIdx.x >> 6;
  int wm = (w >> 1) * 64, wn = (w & 1) * 64;
#pragma unroll
  for (int mi = 0; mi < 4; ++mi) {
#pragma unroll
    for (int ni = 0; ni < 4; ++ni) {
      f32x4 v = acc[mi][ni];
      int n = n0 + wn + ni * 16 + (lane & 15);
      float bn = bo[n];
#pragma unroll
      for (int r = 0; r < 4; ++r) {
        int m = m0 + wm + mi * 16 + (lane >> 4) * 4 + r;
        out[(size_t)m * 512 + n] = v[r] + bn;
      }
    }
  }
}

// ---------------- launch ----------------

extern "C" void kernel_launch(void* const* d_in, const int* in_sizes, int n_in,
                              void* d_out, int out_size, void* d_ws, size_t ws_size,
                              hipStream_t stream) {
  (void)in_sizes; (void)n_in; (void)out_size;
  const float* x  = (const float*)d_in[0];
  const float* wq = (const float*)d_in[1];
  const float* bq = (const float*)d_in[2];
  const float* wk = (const float*)d_in[3];
  const float* bk = (const float*)d_in[4];
  const float* wv = (const float*)d_in[5];
  const float* bv = (const float*)d_in[6];
  const float* wo = (const float*)d_in[7];
  const float* bo = (const float*)d_in[8];
  float* out = (float*)d_out;

  // Head-group count: largest G (fewest groups) whose footprint fits ws_size.
  const size_t SLAB = (size_t)4 * 2048 * 512 * 2;  // one head's q/k/v (4 batches), 8 MB
  const size_t FIXED = (size_t)8192 * 512 * 2      // xb
                     + (size_t)24 * 512 * 512 * 2  // wt
                     + (size_t)512 * 4096 * 2      // wot
                     + (size_t)2048 * 256 * 8      // cs
                     + (size_t)8192 * 4096 * 2;    // ao
  int G = 8;
  for (int g = 1; g <= 8; g <<= 1) {
    if (FIXED + 3 * (size_t)(8 / g) * SLAB <= ws_size) { G = g; break; }
  }
  const int hp = 8 / G;
  int hp_log2 = 0;
  while ((1 << hp_log2) < hp) ++hp_log2;

  char* p = (char*)d_ws;
  unsigned short* xb  = (unsigned short*)p; p += (size_t)8192 * 512 * 2;
  unsigned short* wt  = (unsigned short*)p; p += (size_t)24 * 512 * 512 * 2;
  unsigned short* wot = (unsigned short*)p; p += (size_t)512 * 4096 * 2;
  float2*         cs  = (float2*)p;         p += (size_t)2048 * 256 * 8;
  unsigned short* ao  = (unsigned short*)p; p += (size_t)8192 * 4096 * 2;
  unsigned short* qb  = (unsigned short*)p; p += (size_t)hp * SLAB;
  unsigned short* kb  = (unsigned short*)p; p += (size_t)hp * SLAB;
  unsigned short* vt  = (unsigned short*)p; p += (size_t)hp * SLAB;

  hipLaunchKernelGGL(k_cvt_x,   dim3(4096),     dim3(256), 0, stream, x, xb);
  hipLaunchKernelGGL(k_pack_w,  dim3(8, 8, 24), dim3(256), 0, stream, wq, wk, wv, wt);
  hipLaunchKernelGGL(k_pack_wo, dim3(8, 64),    dim3(256), 0, stream, wo, wot);
  hipLaunchKernelGGL(k_cs,      dim3(2048),     dim3(256), 0, stream, cs);

  for (int g = 0; g < G; ++g) {
    int nhb = 4 * hp;
    hipLaunchKernelGGL(k_gemm_qk, dim3(64, 8 * hp), dim3(256), 0, stream,
                       xb, wt, bq, bk, cs, qb, kb, hp_log2, g * hp);
    hipLaunchKernelGGL(k_gemm_vt, dim3(4 * hp, 64), dim3(256), 0, stream,
                       xb, wt, bv, vt, g * hp * 512);
    hipLaunchKernelGGL(k_attn,    dim3(16 * nhb),   dim3(256), 0, stream,
                       qb, kb, vt, ao, nhb, g * hp);
  }

  hipLaunchKernelGGL(k_gemm_out, dim3(64, 4), dim3(256), 0, stream, ao, wot, bo, out);
}